// Round 1
// baseline (322.498 us; speedup 1.0000x reference)
//
#include <hip/hip_runtime.h>
#include <float.h>
#include <math.h>

#define SEQ 2048
#define NB 4
#define DIM 128
#define DL 16
#define NEGV (-1e9f)
#define TOPK 8

// ---------------------------------------------------------------------------
// Kernel A: q_low/k_low projections + per-key high-rank correction scalar sh.
// sh[b,t] = 0.25 * dot(q[b,t]@Wq_high + bq_high, k[b,t]@Wk_high + bk_high)
// (score_high depends only on the gathered index, so precompute per key.)
// ---------------------------------------------------------------------------
__global__ __launch_bounds__(256) void proj_kernel(
    const float* __restrict__ q, const float* __restrict__ k,
    const float* __restrict__ Wql, const float* __restrict__ bql,
    const float* __restrict__ Wkl, const float* __restrict__ bkl,
    const float* __restrict__ Wqh, const float* __restrict__ bqh,
    const float* __restrict__ Wkh, const float* __restrict__ bkh,
    float* __restrict__ q_low, float* __restrict__ k_low,
    float* __restrict__ sh)
{
    __shared__ float Ws[4][DIM * DL];   // 32 KB
    __shared__ float rowq[16][DIM];     // 8 KB
    __shared__ float rowk[16][DIM];     // 8 KB
    int tid = threadIdx.x;
    for (int i = tid; i < DIM * DL; i += 256) {
        Ws[0][i] = Wql[i];
        Ws[1][i] = Wkl[i];
        Ws[2][i] = Wqh[i];
        Ws[3][i] = Wkh[i];
    }
    int r0 = blockIdx.x * 16;
    for (int i = tid; i < 16 * DIM; i += 256) {
        int rr = i >> 7, cc = i & 127;
        rowq[rr][cc] = q[(size_t)(r0 + rr) * DIM + cc];
        rowk[rr][cc] = k[(size_t)(r0 + rr) * DIM + cc];
    }
    __syncthreads();
    int g = tid >> 4;    // row within block
    int e = tid & 15;    // output element
    float aql = 0.f, akl = 0.f, aqh = 0.f, akh = 0.f;
    #pragma unroll 8
    for (int i = 0; i < DIM; ++i) {
        float qv = rowq[g][i], kv = rowk[g][i];
        aql = fmaf(qv, Ws[0][i * DL + e], aql);
        akl = fmaf(kv, Ws[1][i * DL + e], akl);
        aqh = fmaf(qv, Ws[2][i * DL + e], aqh);
        akh = fmaf(kv, Ws[3][i * DL + e], akh);
    }
    int t = r0 + g;
    q_low[(size_t)t * DL + e] = aql + bql[e];
    k_low[(size_t)t * DL + e] = akl + bkl[e];
    float qp = aqh + bqh[e];
    float kp = akh + bkh[e];
    float prod = qp * kp;
    #pragma unroll
    for (int off = 8; off >= 1; off >>= 1)
        prod += __shfl_xor(prod, off, 16);
    if (e == 0) sh[t] = 0.25f * prod;
}

// ---------------------------------------------------------------------------
// Kernel B: one block per (b,q) row. Compute 2048 masked low-rank scores
// (8 per thread in registers), 8 argmax rounds (tie -> smaller index, matching
// lax.top_k), replace winners with sh[b,k], write the row to Smat.
// ---------------------------------------------------------------------------
__global__ __launch_bounds__(256) void score_topk_kernel(
    const float* __restrict__ q_low, const float* __restrict__ k_low,
    const float* __restrict__ sh, const int* __restrict__ valid_lens,
    float* __restrict__ Smat)
{
    int qi = blockIdx.x;
    int b  = blockIdx.y;
    int tid = threadIdx.x;
    __shared__ float qv[DL];
    __shared__ float red_v[4];
    __shared__ int   red_i[4];
    if (tid < DL) qv[tid] = q_low[((size_t)b * SEQ + qi) * DL + tid];
    __syncthreads();

    const float* kb = k_low + (size_t)b * SEQ * DL;
    const int*   vl = valid_lens + (size_t)b * SEQ;

    float orig[8], work[8];
    #pragma unroll
    for (int j = 0; j < 8; ++j) {
        int kcol = tid + j * 256;
        const float4* kp4 = (const float4*)(kb + (size_t)kcol * DL);
        float acc = 0.f;
        #pragma unroll
        for (int e4 = 0; e4 < 4; ++e4) {
            float4 v = kp4[e4];
            acc += qv[e4 * 4 + 0] * v.x + qv[e4 * 4 + 1] * v.y +
                   qv[e4 * 4 + 2] * v.z + qv[e4 * 4 + 3] * v.w;
        }
        acc *= 0.25f;
        int vli = vl[kcol];
        vli = vli < 0 ? 0 : (vli > SEQ - 1 ? SEQ - 1 : vli);
        if (vli == qi) acc += NEGV;   // mask: add -1e9 (reference adds, not sets)
        orig[j] = acc;
        work[j] = acc;
    }

    for (int r = 0; r < TOPK; ++r) {
        // local best over 8 (earlier j = smaller global index wins ties)
        float bv = work[0]; int bj = 0;
        #pragma unroll
        for (int j = 1; j < 8; ++j)
            if (work[j] > bv) { bv = work[j]; bj = j; }
        int bidx = tid + bj * 256;
        // wave reduce (64 lanes), tie -> smaller index
        #pragma unroll
        for (int off = 32; off >= 1; off >>= 1) {
            float ov = __shfl_xor(bv, off, 64);
            int   oi = __shfl_xor(bidx, off, 64);
            if (ov > bv || (ov == bv && oi < bidx)) { bv = ov; bidx = oi; }
        }
        int wid = tid >> 6;
        if ((tid & 63) == 0) { red_v[wid] = bv; red_i[wid] = bidx; }
        __syncthreads();
        float gv = red_v[0]; int gi = red_i[0];
        #pragma unroll
        for (int w = 1; w < 4; ++w)
            if (red_v[w] > gv || (red_v[w] == gv && red_i[w] < gi)) {
                gv = red_v[w]; gi = red_i[w];
            }
        if (tid == (gi & 255)) {
            int j = gi >> 8;
            float shv = sh[(size_t)b * SEQ + gi];
            #pragma unroll
            for (int jj = 0; jj < 8; ++jj)
                if (jj == j) { work[jj] = -FLT_MAX; orig[jj] = shv; }
        }
        __syncthreads();   // protect red_v/red_i reuse next round
    }

    float* Srow = Smat + ((size_t)b * SEQ + qi) * SEQ;
    #pragma unroll
    for (int j = 0; j < 8; ++j)
        Srow[tid + j * 256] = orig[j];
}

// ---------------------------------------------------------------------------
// Kernel C1: per-column (over q) online softmax partials, q chunked by 128.
// Threads stride along k -> coalesced row reads.
// ---------------------------------------------------------------------------
__global__ __launch_bounds__(256) void colred_partial(
    const float* __restrict__ Smat, float* __restrict__ pm, float* __restrict__ pl)
{
    int kcol = blockIdx.x * 256 + threadIdx.x;
    int qc = blockIdx.y;  // 0..15
    int b  = blockIdx.z;
    const float* Sp = Smat + (size_t)b * SEQ * SEQ + (size_t)(qc * 128) * SEQ + kcol;
    float m = -FLT_MAX, l = 0.f;
    for (int qq = 0; qq < 128; ++qq) {
        float v = Sp[(size_t)qq * SEQ];
        float nm = fmaxf(m, v);
        l = l * __expf(m - nm) + __expf(v - nm);
        m = nm;
    }
    pm[((size_t)b * 16 + qc) * SEQ + kcol] = m;
    pl[((size_t)b * 16 + qc) * SEQ + kcol] = l;
}

// Kernel C2: combine 16 chunk partials -> column max & 1/sum.
__global__ __launch_bounds__(256) void colred_final(
    const float* __restrict__ pm, const float* __restrict__ pl,
    float* __restrict__ cmax, float* __restrict__ cinv)
{
    int idx = blockIdx.x * 256 + threadIdx.x;  // 0..8191
    int b = idx >> 11, kcol = idx & (SEQ - 1);
    float m = -FLT_MAX, l = 0.f;
    #pragma unroll
    for (int c = 0; c < 16; ++c) {
        float mm = pm[((size_t)b * 16 + c) * SEQ + kcol];
        float ll = pl[((size_t)b * 16 + c) * SEQ + kcol];
        float nm = fmaxf(m, mm);
        l = l * __expf(m - nm) + ll * __expf(mm - nm);
        m = nm;
    }
    cmax[idx] = m;
    cinv[idx] = 1.f / l;
}

// ---------------------------------------------------------------------------
// Kernel D: out[b,q,:] = sum_k exp(S-cmax[k])*cinv[k] * V[b,k,:]
// Tile: BQ=32 q-rows x full d=128, k chunks of 64. V chunk + P tile in LDS.
// ---------------------------------------------------------------------------
__global__ __launch_bounds__(256) void out_kernel(
    const float* __restrict__ Smat, const float* __restrict__ values,
    const float* __restrict__ cmax, const float* __restrict__ cinv,
    float* __restrict__ out)
{
    __shared__ float Vt[64 * 128];     // 32 KB
    __shared__ float Pt[32 * 65];      // padded stride 65 -> no ty bank conflict
    int tid = threadIdx.x;
    int q0 = blockIdx.x * 32;
    int b  = blockIdx.y;
    int ty = tid >> 4, tx = tid & 15;

    float acc[2][8];
    #pragma unroll
    for (int r = 0; r < 2; ++r)
        #pragma unroll
        for (int j = 0; j < 8; ++j) acc[r][j] = 0.f;

    const float* Sb = Smat + (size_t)b * SEQ * SEQ;
    const float* Vb = values + (size_t)b * SEQ * DIM;
    const float* cm = cmax + (size_t)b * SEQ;
    const float* ci = cinv + (size_t)b * SEQ;

    for (int k0 = 0; k0 < SEQ; k0 += 64) {
        // stage V chunk [64][128]
        const float4* Vg4 = (const float4*)(Vb + (size_t)k0 * DIM);
        float4* Vt4 = (float4*)Vt;
        #pragma unroll
        for (int v = 0; v < 8; ++v)
            Vt4[tid + v * 256] = Vg4[tid + v * 256];
        // compute P tile [32][64]
        {
            int qq = tid >> 3;
            int kbase = (tid & 7) * 8;
            const float* Srow = Sb + (size_t)(q0 + qq) * SEQ + k0 + kbase;
            #pragma unroll
            for (int jj = 0; jj < 8; ++jj) {
                int kcol = k0 + kbase + jj;
                Pt[qq * 65 + kbase + jj] = __expf(Srow[jj] - cm[kcol]) * ci[kcol];
            }
        }
        __syncthreads();
        #pragma unroll 8
        for (int kk = 0; kk < 64; ++kk) {
            float p0 = Pt[(ty * 2 + 0) * 65 + kk];
            float p1 = Pt[(ty * 2 + 1) * 65 + kk];
            const float4* Vr = (const float4*)(&Vt[kk * 128]);
            float4 va = Vr[tx * 2];
            float4 vb = Vr[tx * 2 + 1];
            acc[0][0] = fmaf(p0, va.x, acc[0][0]);
            acc[0][1] = fmaf(p0, va.y, acc[0][1]);
            acc[0][2] = fmaf(p0, va.z, acc[0][2]);
            acc[0][3] = fmaf(p0, va.w, acc[0][3]);
            acc[0][4] = fmaf(p0, vb.x, acc[0][4]);
            acc[0][5] = fmaf(p0, vb.y, acc[0][5]);
            acc[0][6] = fmaf(p0, vb.z, acc[0][6]);
            acc[0][7] = fmaf(p0, vb.w, acc[0][7]);
            acc[1][0] = fmaf(p1, va.x, acc[1][0]);
            acc[1][1] = fmaf(p1, va.y, acc[1][1]);
            acc[1][2] = fmaf(p1, va.z, acc[1][2]);
            acc[1][3] = fmaf(p1, va.w, acc[1][3]);
            acc[1][4] = fmaf(p1, vb.x, acc[1][4]);
            acc[1][5] = fmaf(p1, vb.y, acc[1][5]);
            acc[1][6] = fmaf(p1, vb.z, acc[1][6]);
            acc[1][7] = fmaf(p1, vb.w, acc[1][7]);
        }
        __syncthreads();
    }

    #pragma unroll
    for (int r = 0; r < 2; ++r) {
        int qa = q0 + ty * 2 + r;
        float4* o = (float4*)(out + ((size_t)b * SEQ + qa) * DIM + tx * 8);
        o[0] = make_float4(acc[r][0], acc[r][1], acc[r][2], acc[r][3]);
        o[1] = make_float4(acc[r][4], acc[r][5], acc[r][6], acc[r][7]);
    }
}

extern "C" void kernel_launch(void* const* d_in, const int* in_sizes, int n_in,
                              void* d_out, int out_size, void* d_ws, size_t ws_size,
                              hipStream_t stream)
{
    const float* queries = (const float*)d_in[0];
    const float* keys    = (const float*)d_in[1];
    const float* values  = (const float*)d_in[2];
    const int*   valid   = (const int*)d_in[3];
    const float* Wql = (const float*)d_in[4];
    const float* bql = (const float*)d_in[5];
    const float* Wkl = (const float*)d_in[6];
    const float* bkl = (const float*)d_in[7];
    const float* Wqh = (const float*)d_in[8];
    const float* bqh = (const float*)d_in[9];
    const float* Wkh = (const float*)d_in[10];
    const float* bkh = (const float*)d_in[11];

    char* ws = (char*)d_ws;
    // layout (bytes)
    float* Smat  = (float*)(ws);                       // 4*2048*2048*4 = 64 MB
    float* q_low = (float*)(ws + 67108864);            // 512 KB
    float* k_low = (float*)(ws + 67108864 + 524288);   // 512 KB
    float* sh    = (float*)(ws + 67108864 + 1048576);  // 32 KB
    float* pm    = (float*)(ws + 67108864 + 1081344);  // 512 KB
    float* pl    = (float*)(ws + 67108864 + 1605632);  // 512 KB
    float* cmax  = (float*)(ws + 67108864 + 2129920);  // 32 KB
    float* cinv  = (float*)(ws + 67108864 + 2162688);  // 32 KB

    proj_kernel<<<dim3((NB * SEQ) / 16), 256, 0, stream>>>(
        queries, keys, Wql, bql, Wkl, bkl, Wqh, bqh, Wkh, bkh, q_low, k_low, sh);

    score_topk_kernel<<<dim3(SEQ, NB), 256, 0, stream>>>(
        q_low, k_low, sh, valid, Smat);

    colred_partial<<<dim3(SEQ / 256, 16, NB), 256, 0, stream>>>(Smat, pm, pl);

    colred_final<<<dim3((NB * SEQ) / 256), 256, 0, stream>>>(pm, pl, cmax, cinv);

    out_kernel<<<dim3(SEQ / 32, NB), 256, 0, stream>>>(
        Smat, values, cmax, cinv, (float*)d_out);
}

// Round 2
// 267.893 us; speedup vs baseline: 1.2038x; 1.2038x over previous
//
#include <hip/hip_runtime.h>
#include <float.h>
#include <math.h>

#define SEQ 2048
#define NB 4
#define DIM 128
#define DL 16
#define NEGV (-1e9f)
#define TOPK 8

#define QT 128      // q-rows per out block
#define KC 64       // k chunk staged in LDS
#define PSTR 132    // Pt row stride (132 ≡ 4 mod 8: 16B-aligned rows, spread banks)

// ---------------------------------------------------------------------------
// Kernel A: q_low/k_low projections + per-key high-rank correction scalar sh.
// ---------------------------------------------------------------------------
__global__ __launch_bounds__(256) void proj_kernel(
    const float* __restrict__ q, const float* __restrict__ k,
    const float* __restrict__ Wql, const float* __restrict__ bql,
    const float* __restrict__ Wkl, const float* __restrict__ bkl,
    const float* __restrict__ Wqh, const float* __restrict__ bqh,
    const float* __restrict__ Wkh, const float* __restrict__ bkh,
    float* __restrict__ q_low, float* __restrict__ k_low,
    float* __restrict__ sh)
{
    __shared__ float Ws[4][DIM * DL];
    __shared__ float rowq[16][DIM];
    __shared__ float rowk[16][DIM];
    int tid = threadIdx.x;
    for (int i = tid; i < DIM * DL; i += 256) {
        Ws[0][i] = Wql[i];
        Ws[1][i] = Wkl[i];
        Ws[2][i] = Wqh[i];
        Ws[3][i] = Wkh[i];
    }
    int r0 = blockIdx.x * 16;
    for (int i = tid; i < 16 * DIM; i += 256) {
        int rr = i >> 7, cc = i & 127;
        rowq[rr][cc] = q[(size_t)(r0 + rr) * DIM + cc];
        rowk[rr][cc] = k[(size_t)(r0 + rr) * DIM + cc];
    }
    __syncthreads();
    int g = tid >> 4;
    int e = tid & 15;
    float aql = 0.f, akl = 0.f, aqh = 0.f, akh = 0.f;
    #pragma unroll 8
    for (int i = 0; i < DIM; ++i) {
        float qv = rowq[g][i], kv = rowk[g][i];
        aql = fmaf(qv, Ws[0][i * DL + e], aql);
        akl = fmaf(kv, Ws[1][i * DL + e], akl);
        aqh = fmaf(qv, Ws[2][i * DL + e], aqh);
        akh = fmaf(kv, Ws[3][i * DL + e], akh);
    }
    int t = r0 + g;
    q_low[(size_t)t * DL + e] = aql + bql[e];
    k_low[(size_t)t * DL + e] = akl + bkl[e];
    float qp = aqh + bqh[e];
    float kp = akh + bkh[e];
    float prod = qp * kp;
    #pragma unroll
    for (int off = 8; off >= 1; off >>= 1)
        prod += __shfl_xor(prod, off, 16);
    if (e == 0) sh[t] = 0.25f * prod;
}

// ---------------------------------------------------------------------------
// Kernel B: one block per (b,q) row: masked low-rank scores, top-8 replace
// with sh, write row.
// ---------------------------------------------------------------------------
__global__ __launch_bounds__(256) void score_topk_kernel(
    const float* __restrict__ q_low, const float* __restrict__ k_low,
    const float* __restrict__ sh, const int* __restrict__ valid_lens,
    float* __restrict__ Smat)
{
    int qi = blockIdx.x;
    int b  = blockIdx.y;
    int tid = threadIdx.x;
    __shared__ float qv[DL];
    __shared__ float red_v[4];
    __shared__ int   red_i[4];
    if (tid < DL) qv[tid] = q_low[((size_t)b * SEQ + qi) * DL + tid];
    __syncthreads();

    const float* kb = k_low + (size_t)b * SEQ * DL;
    const int*   vl = valid_lens + (size_t)b * SEQ;

    float orig[8], work[8];
    #pragma unroll
    for (int j = 0; j < 8; ++j) {
        int kcol = tid + j * 256;
        const float4* kp4 = (const float4*)(kb + (size_t)kcol * DL);
        float acc = 0.f;
        #pragma unroll
        for (int e4 = 0; e4 < 4; ++e4) {
            float4 v = kp4[e4];
            acc += qv[e4 * 4 + 0] * v.x + qv[e4 * 4 + 1] * v.y +
                   qv[e4 * 4 + 2] * v.z + qv[e4 * 4 + 3] * v.w;
        }
        acc *= 0.25f;
        int vli = vl[kcol];
        vli = vli < 0 ? 0 : (vli > SEQ - 1 ? SEQ - 1 : vli);
        if (vli == qi) acc += NEGV;
        orig[j] = acc;
        work[j] = acc;
    }

    for (int r = 0; r < TOPK; ++r) {
        float bv = work[0]; int bj = 0;
        #pragma unroll
        for (int j = 1; j < 8; ++j)
            if (work[j] > bv) { bv = work[j]; bj = j; }
        int bidx = tid + bj * 256;
        #pragma unroll
        for (int off = 32; off >= 1; off >>= 1) {
            float ov = __shfl_xor(bv, off, 64);
            int   oi = __shfl_xor(bidx, off, 64);
            if (ov > bv || (ov == bv && oi < bidx)) { bv = ov; bidx = oi; }
        }
        int wid = tid >> 6;
        if ((tid & 63) == 0) { red_v[wid] = bv; red_i[wid] = bidx; }
        __syncthreads();
        float gv = red_v[0]; int gi = red_i[0];
        #pragma unroll
        for (int w = 1; w < 4; ++w)
            if (red_v[w] > gv || (red_v[w] == gv && red_i[w] < gi)) {
                gv = red_v[w]; gi = red_i[w];
            }
        if (tid == (gi & 255)) {
            int j = gi >> 8;
            float shv = sh[(size_t)b * SEQ + gi];
            #pragma unroll
            for (int jj = 0; jj < 8; ++jj)
                if (jj == j) { work[jj] = -FLT_MAX; orig[jj] = shv; }
        }
        __syncthreads();
    }

    float* Srow = Smat + ((size_t)b * SEQ + qi) * SEQ;
    #pragma unroll
    for (int j = 0; j < 8; ++j)
        Srow[tid + j * 256] = orig[j];
}

// ---------------------------------------------------------------------------
// Kernel C1: per-column (over q) online softmax partials, q chunked by 128.
// ---------------------------------------------------------------------------
__global__ __launch_bounds__(256) void colred_partial(
    const float* __restrict__ Smat, float* __restrict__ pm, float* __restrict__ pl)
{
    int kcol = blockIdx.x * 256 + threadIdx.x;
    int qc = blockIdx.y;
    int b  = blockIdx.z;
    const float* Sp = Smat + (size_t)b * SEQ * SEQ + (size_t)(qc * 128) * SEQ + kcol;
    float m = -FLT_MAX, l = 0.f;
    for (int qq = 0; qq < 128; ++qq) {
        float v = Sp[(size_t)qq * SEQ];
        float nm = fmaxf(m, v);
        l = l * __expf(m - nm) + __expf(v - nm);
        m = nm;
    }
    pm[((size_t)b * 16 + qc) * SEQ + kcol] = m;
    pl[((size_t)b * 16 + qc) * SEQ + kcol] = l;
}

__global__ __launch_bounds__(256) void colred_final(
    const float* __restrict__ pm, const float* __restrict__ pl,
    float* __restrict__ cmax, float* __restrict__ cinv)
{
    int idx = blockIdx.x * 256 + threadIdx.x;
    int b = idx >> 11, kcol = idx & (SEQ - 1);
    float m = -FLT_MAX, l = 0.f;
    #pragma unroll
    for (int c = 0; c < 16; ++c) {
        float mm = pm[((size_t)b * 16 + c) * SEQ + kcol];
        float ll = pl[((size_t)b * 16 + c) * SEQ + kcol];
        float nm = fmaxf(m, mm);
        l = l * __expf(m - nm) + ll * __expf(mm - nm);
        m = nm;
    }
    cmax[idx] = m;
    cinv[idx] = 1.f / l;
}

// ---------------------------------------------------------------------------
// Kernel D v2: partial out over a k-range. QT=128 q-rows per block, 8x8
// register tile per thread, P staged transposed (b128 reads, conflict-free).
// part[ks][b][q][d] if ksplit>1 else direct to out.
// ---------------------------------------------------------------------------
__global__ __launch_bounds__(256, 2) void out_kernel2(
    const float* __restrict__ Smat, const float* __restrict__ values,
    const float* __restrict__ cmax, const float* __restrict__ cinv,
    float* __restrict__ dst, int krange)
{
    __shared__ float Vt[KC * DIM];     // 32 KB
    __shared__ float Pt[KC * PSTR];    // 33.8 KB, Pt[kk][q] transposed

    int tid = threadIdx.x;
    int q0 = blockIdx.x * QT;
    int ks = blockIdx.y;
    int b  = blockIdx.z;
    int kbeg = ks * krange;

    int tx = tid & 15;       // col group: 8 cols at c0
    int ty = tid >> 4;       // row group: 8 rows at r0
    int c0 = tx * 8;
    int r0 = ty * 8;

    float acc[8][8];
    #pragma unroll
    for (int i = 0; i < 8; ++i)
        #pragma unroll
        for (int j = 0; j < 8; ++j) acc[i][j] = 0.f;

    const float* Sb = Smat + (size_t)b * SEQ * SEQ;
    const float* Vb = values + (size_t)b * SEQ * DIM;
    const float* cm = cmax + (size_t)b * SEQ;
    const float* ci = cinv + (size_t)b * SEQ;

    for (int k0 = kbeg; k0 < kbeg + krange; k0 += KC) {
        // stage V chunk [KC][DIM]
        const float4* Vg4 = (const float4*)(Vb + (size_t)k0 * DIM);
        float4* Vt4 = (float4*)Vt;
        #pragma unroll
        for (int v = 0; v < 8; ++v)
            Vt4[tid + v * 256] = Vg4[tid + v * 256];
        // stage P transposed: thread owns kk4..kk4+3 cols of S rows
        {
            int kk4 = (tid & 15) * 4;
            int qrow0 = tid >> 4;
            float4 cmv = *(const float4*)(cm + k0 + kk4);
            float4 civ = *(const float4*)(ci + k0 + kk4);
            #pragma unroll
            for (int it = 0; it < 8; ++it) {
                int qq = qrow0 + it * 16;
                float4 s = *(const float4*)(Sb + (size_t)(q0 + qq) * SEQ + k0 + kk4);
                Pt[(kk4 + 0) * PSTR + qq] = __expf(s.x - cmv.x) * civ.x;
                Pt[(kk4 + 1) * PSTR + qq] = __expf(s.y - cmv.y) * civ.y;
                Pt[(kk4 + 2) * PSTR + qq] = __expf(s.z - cmv.z) * civ.z;
                Pt[(kk4 + 3) * PSTR + qq] = __expf(s.w - cmv.w) * civ.w;
            }
        }
        __syncthreads();
        #pragma unroll 2
        for (int kk = 0; kk < KC; ++kk) {
            float4 pa = *(const float4*)&Pt[kk * PSTR + r0];
            float4 pb = *(const float4*)&Pt[kk * PSTR + r0 + 4];
            float4 va = *(const float4*)&Vt[kk * DIM + c0];
            float4 vb = *(const float4*)&Vt[kk * DIM + c0 + 4];
            float p[8] = {pa.x, pa.y, pa.z, pa.w, pb.x, pb.y, pb.z, pb.w};
            float v[8] = {va.x, va.y, va.z, va.w, vb.x, vb.y, vb.z, vb.w};
            #pragma unroll
            for (int i = 0; i < 8; ++i)
                #pragma unroll
                for (int j = 0; j < 8; ++j)
                    acc[i][j] = fmaf(p[i], v[j], acc[i][j]);
        }
        __syncthreads();
    }

    float* dp = dst + (size_t)ks * ((size_t)NB * SEQ * DIM) + (size_t)b * SEQ * DIM;
    #pragma unroll
    for (int i = 0; i < 8; ++i) {
        float* o = dp + (size_t)(q0 + r0 + i) * DIM + c0;
        *(float4*)(o)     = make_float4(acc[i][0], acc[i][1], acc[i][2], acc[i][3]);
        *(float4*)(o + 4) = make_float4(acc[i][4], acc[i][5], acc[i][6], acc[i][7]);
    }
}

// sum ksplit partials -> out
__global__ __launch_bounds__(256) void reduce_kernel(
    const float* __restrict__ part, float* __restrict__ out, int ksplit)
{
    int idx = blockIdx.x * 256 + threadIdx.x;   // float4 index, 262144 total
    const float4* p = (const float4*)part;
    float4 a = p[idx];
    for (int s = 1; s < ksplit; ++s) {
        float4 q = p[(size_t)idx + (size_t)s * 262144];
        a.x += q.x; a.y += q.y; a.z += q.z; a.w += q.w;
    }
    ((float4*)out)[idx] = a;
}

extern "C" void kernel_launch(void* const* d_in, const int* in_sizes, int n_in,
                              void* d_out, int out_size, void* d_ws, size_t ws_size,
                              hipStream_t stream)
{
    const float* queries = (const float*)d_in[0];
    const float* keys    = (const float*)d_in[1];
    const float* values  = (const float*)d_in[2];
    const int*   valid   = (const int*)d_in[3];
    const float* Wql = (const float*)d_in[4];
    const float* bql = (const float*)d_in[5];
    const float* Wkl = (const float*)d_in[6];
    const float* bkl = (const float*)d_in[7];
    const float* Wqh = (const float*)d_in[8];
    const float* bqh = (const float*)d_in[9];
    const float* Wkh = (const float*)d_in[10];
    const float* bkh = (const float*)d_in[11];

    char* ws = (char*)d_ws;
    float* Smat  = (float*)(ws);                       // 64 MB
    float* q_low = (float*)(ws + 67108864);            // 512 KB
    float* k_low = (float*)(ws + 67108864 + 524288);   // 512 KB
    float* sh    = (float*)(ws + 67108864 + 1048576);  // 32 KB
    float* pm    = (float*)(ws + 67108864 + 1081344);  // 512 KB
    float* pl    = (float*)(ws + 67108864 + 1605632);  // 512 KB
    float* cmax  = (float*)(ws + 67108864 + 2129920);  // 32 KB
    float* cinv  = (float*)(ws + 67108864 + 2162688);  // 32 KB

    const size_t part_off = 73400320;                  // 70 MiB
    const size_t part_sz  = (size_t)NB * SEQ * DIM * 4; // 4 MiB per split
    int ksplit = 1;
    if      (ws_size >= part_off + 8 * part_sz) ksplit = 8;
    else if (ws_size >= part_off + 4 * part_sz) ksplit = 4;
    else if (ws_size >= part_off + 2 * part_sz) ksplit = 2;
    float* part = (float*)(ws + part_off);

    proj_kernel<<<dim3((NB * SEQ) / 16), 256, 0, stream>>>(
        queries, keys, Wql, bql, Wkl, bkl, Wqh, bqh, Wkh, bkh, q_low, k_low, sh);

    score_topk_kernel<<<dim3(SEQ, NB), 256, 0, stream>>>(
        q_low, k_low, sh, valid, Smat);

    colred_partial<<<dim3(SEQ / 256, 16, NB), 256, 0, stream>>>(Smat, pm, pl);

    colred_final<<<dim3((NB * SEQ) / 256), 256, 0, stream>>>(pm, pl, cmax, cinv);

    if (ksplit == 1) {
        out_kernel2<<<dim3(SEQ / QT, 1, NB), 256, 0, stream>>>(
            Smat, values, cmax, cinv, (float*)d_out, SEQ);
    } else {
        out_kernel2<<<dim3(SEQ / QT, ksplit, NB), 256, 0, stream>>>(
            Smat, values, cmax, cinv, part, SEQ / ksplit);
        reduce_kernel<<<(NB * SEQ * DIM / 4) / 256, 256, 0, stream>>>(
            part, (float*)d_out, ksplit);
    }
}

// Round 3
// 238.030 us; speedup vs baseline: 1.3549x; 1.1255x over previous
//
#include <hip/hip_runtime.h>
#include <float.h>
#include <math.h>

#define SEQ 2048
#define NB 4
#define DIM 128
#define DL 16
#define NEGV (-1e9f)
#define TOPK 8

#define QT 128      // q-rows per out block
#define KC 64       // k chunk staged in LDS
#define PSTR 132    // Pt row stride

typedef unsigned long long u64;

// ---------------------------------------------------------------------------
// Kernel A: q_low/k_low projections + per-key high-rank correction scalar sh.
// ---------------------------------------------------------------------------
__global__ __launch_bounds__(256) void proj_kernel(
    const float* __restrict__ q, const float* __restrict__ k,
    const float* __restrict__ Wql, const float* __restrict__ bql,
    const float* __restrict__ Wkl, const float* __restrict__ bkl,
    const float* __restrict__ Wqh, const float* __restrict__ bqh,
    const float* __restrict__ Wkh, const float* __restrict__ bkh,
    float* __restrict__ q_low, float* __restrict__ k_low,
    float* __restrict__ sh)
{
    __shared__ float Ws[4][DIM * DL];
    __shared__ float rowq[16][DIM];
    __shared__ float rowk[16][DIM];
    int tid = threadIdx.x;
    for (int i = tid; i < DIM * DL; i += 256) {
        Ws[0][i] = Wql[i];
        Ws[1][i] = Wkl[i];
        Ws[2][i] = Wqh[i];
        Ws[3][i] = Wkh[i];
    }
    int r0 = blockIdx.x * 16;
    for (int i = tid; i < 16 * DIM; i += 256) {
        int rr = i >> 7, cc = i & 127;
        rowq[rr][cc] = q[(size_t)(r0 + rr) * DIM + cc];
        rowk[rr][cc] = k[(size_t)(r0 + rr) * DIM + cc];
    }
    __syncthreads();
    int g = tid >> 4;
    int e = tid & 15;
    float aql = 0.f, akl = 0.f, aqh = 0.f, akh = 0.f;
    #pragma unroll 8
    for (int i = 0; i < DIM; ++i) {
        float qv = rowq[g][i], kv = rowk[g][i];
        aql = fmaf(qv, Ws[0][i * DL + e], aql);
        akl = fmaf(kv, Ws[1][i * DL + e], akl);
        aqh = fmaf(qv, Ws[2][i * DL + e], aqh);
        akh = fmaf(kv, Ws[3][i * DL + e], akh);
    }
    int t = r0 + g;
    q_low[(size_t)t * DL + e] = aql + bql[e];
    k_low[(size_t)t * DL + e] = akl + bkl[e];
    float qp = aqh + bqh[e];
    float kp = akh + bkh[e];
    float prod = qp * kp;
    #pragma unroll
    for (int off = 8; off >= 1; off >>= 1)
        prod += __shfl_xor(prod, off, 16);
    if (e == 0) sh[t] = 0.25f * prod;
}

// ---------------------------------------------------------------------------
// Kernel B v3: one WAVE per (b,q) row, barrier-free. Each lane: 32 cols,
// masked score -> Smat (unpatched), u64 key ((mono<<11)|(2047-col)) into a
// lane-local sorted top-8 (CE chain), then 6-stage butterfly bitonic merge.
// Lane 0 writes the row's top-8 indices. Exact order, ties -> smaller index.
// ---------------------------------------------------------------------------
__device__ __forceinline__ void ce_desc(u64& a, u64& b) {
    u64 mx = a > b ? a : b;
    u64 mn = a > b ? b : a;
    a = mx; b = mn;
}

__global__ __launch_bounds__(256) void score_topk3(
    const float* __restrict__ q_low, const float* __restrict__ k_low,
    const int* __restrict__ valid_lens, float* __restrict__ Smat,
    int* __restrict__ topk_idx)
{
    int lane = threadIdx.x & 63;
    int wv   = threadIdx.x >> 6;
    int row  = __builtin_amdgcn_readfirstlane(blockIdx.x * 4 + wv); // 0..8191
    int b    = row >> 11;
    int qi   = row & (SEQ - 1);

    const float* qp = q_low + (size_t)row * DL;
    float qv[16];
    #pragma unroll
    for (int e = 0; e < 16; ++e) qv[e] = qp[e];

    const float* kb = k_low + (size_t)b * SEQ * DL;
    const int*   vl = valid_lens + (size_t)b * SEQ;
    float* Srow = Smat + (size_t)row * SEQ;

    u64 s[8];
    #pragma unroll
    for (int i = 0; i < 8; ++i) s[i] = 0ULL;

    #pragma unroll 2
    for (int j = 0; j < 32; ++j) {
        int col = lane + j * 64;
        const float4* kp4 = (const float4*)(kb + (size_t)col * DL);
        float4 v0 = kp4[0], v1 = kp4[1], v2 = kp4[2], v3 = kp4[3];
        float acc = 0.f;
        acc = fmaf(qv[0],  v0.x, acc); acc = fmaf(qv[1],  v0.y, acc);
        acc = fmaf(qv[2],  v0.z, acc); acc = fmaf(qv[3],  v0.w, acc);
        acc = fmaf(qv[4],  v1.x, acc); acc = fmaf(qv[5],  v1.y, acc);
        acc = fmaf(qv[6],  v1.z, acc); acc = fmaf(qv[7],  v1.w, acc);
        acc = fmaf(qv[8],  v2.x, acc); acc = fmaf(qv[9],  v2.y, acc);
        acc = fmaf(qv[10], v2.z, acc); acc = fmaf(qv[11], v2.w, acc);
        acc = fmaf(qv[12], v3.x, acc); acc = fmaf(qv[13], v3.y, acc);
        acc = fmaf(qv[14], v3.z, acc); acc = fmaf(qv[15], v3.w, acc);
        acc *= 0.25f;
        int vli = vl[col];
        vli = vli < 0 ? 0 : (vli > SEQ - 1 ? SEQ - 1 : vli);
        if (vli == qi) acc += NEGV;
        Srow[col] = acc;

        unsigned u = __float_as_uint(acc);
        u ^= ((unsigned)((int)u >> 31)) | 0x80000000u;
        u64 key = ((u64)u << 11) | (unsigned)(SEQ - 1 - col);

        #pragma unroll
        for (int i = 0; i < 8; ++i) {
            bool g = key > s[i];
            u64 ns = g ? key : s[i];
            key    = g ? s[i] : key;
            s[i] = ns;
        }
    }

    // butterfly merge of sorted-8 (desc) lists across 64 lanes
    #pragma unroll
    for (int off = 1; off < 64; off <<= 1) {
        u64 o[8];
        #pragma unroll
        for (int i = 0; i < 8; ++i)
            o[i] = __shfl_xor(s[i], off, 64);
        u64 t[8];
        #pragma unroll
        for (int i = 0; i < 8; ++i) {
            u64 x = o[7 - i];
            t[i] = s[i] > x ? s[i] : x;
        }
        // t is bitonic; sort descending: CE distances 4, 2, 1
        ce_desc(t[0], t[4]); ce_desc(t[1], t[5]);
        ce_desc(t[2], t[6]); ce_desc(t[3], t[7]);
        ce_desc(t[0], t[2]); ce_desc(t[1], t[3]);
        ce_desc(t[4], t[6]); ce_desc(t[5], t[7]);
        ce_desc(t[0], t[1]); ce_desc(t[2], t[3]);
        ce_desc(t[4], t[5]); ce_desc(t[6], t[7]);
        #pragma unroll
        for (int i = 0; i < 8; ++i) s[i] = t[i];
    }

    if (lane == 0) {
        #pragma unroll
        for (int i = 0; i < 8; ++i)
            topk_idx[(size_t)row * 8 + i] = (SEQ - 1) - (int)(s[i] & 0x7FF);
    }
}

// patch sh into the top-8 positions of each row
__global__ __launch_bounds__(256) void scatter_kernel(
    const int* __restrict__ topk_idx, const float* __restrict__ sh,
    float* __restrict__ Smat)
{
    int t = blockIdx.x * 256 + threadIdx.x;   // 0..65535
    int row = t >> 3;
    int b = row >> 11;
    int idx = topk_idx[t];
    Smat[(size_t)row * SEQ + idx] = sh[(size_t)b * SEQ + idx];
}

// ---------------------------------------------------------------------------
// Kernel C1: per-column (over q) online softmax partials, q chunked by 128.
// ---------------------------------------------------------------------------
__global__ __launch_bounds__(256) void colred_partial(
    const float* __restrict__ Smat, float* __restrict__ pm, float* __restrict__ pl)
{
    int kcol = blockIdx.x * 256 + threadIdx.x;
    int qc = blockIdx.y;
    int b  = blockIdx.z;
    const float* Sp = Smat + (size_t)b * SEQ * SEQ + (size_t)(qc * 128) * SEQ + kcol;
    float m = -FLT_MAX, l = 0.f;
    for (int qq = 0; qq < 128; ++qq) {
        float v = Sp[(size_t)qq * SEQ];
        float nm = fmaxf(m, v);
        l = l * __expf(m - nm) + __expf(v - nm);
        m = nm;
    }
    pm[((size_t)b * 16 + qc) * SEQ + kcol] = m;
    pl[((size_t)b * 16 + qc) * SEQ + kcol] = l;
}

__global__ __launch_bounds__(256) void colred_final(
    const float* __restrict__ pm, const float* __restrict__ pl,
    float* __restrict__ cmax, float* __restrict__ cinv)
{
    int idx = blockIdx.x * 256 + threadIdx.x;
    int b = idx >> 11, kcol = idx & (SEQ - 1);
    float m = -FLT_MAX, l = 0.f;
    #pragma unroll
    for (int c = 0; c < 16; ++c) {
        float mm = pm[((size_t)b * 16 + c) * SEQ + kcol];
        float ll = pl[((size_t)b * 16 + c) * SEQ + kcol];
        float nm = fmaxf(m, mm);
        l = l * __expf(m - nm) + ll * __expf(mm - nm);
        m = nm;
    }
    cmax[idx] = m;
    cinv[idx] = 1.f / l;
}

// ---------------------------------------------------------------------------
// Kernel D v2: partial out over a k-range. QT=128 q-rows per block, 8x8
// register tile per thread, P staged transposed.
// ---------------------------------------------------------------------------
__global__ __launch_bounds__(256, 2) void out_kernel2(
    const float* __restrict__ Smat, const float* __restrict__ values,
    const float* __restrict__ cmax, const float* __restrict__ cinv,
    float* __restrict__ dst, int krange)
{
    __shared__ float Vt[KC * DIM];
    __shared__ float Pt[KC * PSTR];

    int tid = threadIdx.x;
    int q0 = blockIdx.x * QT;
    int ks = blockIdx.y;
    int b  = blockIdx.z;
    int kbeg = ks * krange;

    int tx = tid & 15;
    int ty = tid >> 4;
    int c0 = tx * 8;
    int r0 = ty * 8;

    float acc[8][8];
    #pragma unroll
    for (int i = 0; i < 8; ++i)
        #pragma unroll
        for (int j = 0; j < 8; ++j) acc[i][j] = 0.f;

    const float* Sb = Smat + (size_t)b * SEQ * SEQ;
    const float* Vb = values + (size_t)b * SEQ * DIM;
    const float* cm = cmax + (size_t)b * SEQ;
    const float* ci = cinv + (size_t)b * SEQ;

    for (int k0 = kbeg; k0 < kbeg + krange; k0 += KC) {
        const float4* Vg4 = (const float4*)(Vb + (size_t)k0 * DIM);
        float4* Vt4 = (float4*)Vt;
        #pragma unroll
        for (int v = 0; v < 8; ++v)
            Vt4[tid + v * 256] = Vg4[tid + v * 256];
        {
            int kk4 = (tid & 15) * 4;
            int qrow0 = tid >> 4;
            float4 cmv = *(const float4*)(cm + k0 + kk4);
            float4 civ = *(const float4*)(ci + k0 + kk4);
            #pragma unroll
            for (int it = 0; it < 8; ++it) {
                int qq = qrow0 + it * 16;
                float4 s = *(const float4*)(Sb + (size_t)(q0 + qq) * SEQ + k0 + kk4);
                Pt[(kk4 + 0) * PSTR + qq] = __expf(s.x - cmv.x) * civ.x;
                Pt[(kk4 + 1) * PSTR + qq] = __expf(s.y - cmv.y) * civ.y;
                Pt[(kk4 + 2) * PSTR + qq] = __expf(s.z - cmv.z) * civ.z;
                Pt[(kk4 + 3) * PSTR + qq] = __expf(s.w - cmv.w) * civ.w;
            }
        }
        __syncthreads();
        #pragma unroll 2
        for (int kk = 0; kk < KC; ++kk) {
            float4 pa = *(const float4*)&Pt[kk * PSTR + r0];
            float4 pb = *(const float4*)&Pt[kk * PSTR + r0 + 4];
            float4 va = *(const float4*)&Vt[kk * DIM + c0];
            float4 vb = *(const float4*)&Vt[kk * DIM + c0 + 4];
            float p[8] = {pa.x, pa.y, pa.z, pa.w, pb.x, pb.y, pb.z, pb.w};
            float v[8] = {va.x, va.y, va.z, va.w, vb.x, vb.y, vb.z, vb.w};
            #pragma unroll
            for (int i = 0; i < 8; ++i)
                #pragma unroll
                for (int j = 0; j < 8; ++j)
                    acc[i][j] = fmaf(p[i], v[j], acc[i][j]);
        }
        __syncthreads();
    }

    float* dp = dst + (size_t)ks * ((size_t)NB * SEQ * DIM) + (size_t)b * SEQ * DIM;
    #pragma unroll
    for (int i = 0; i < 8; ++i) {
        float* o = dp + (size_t)(q0 + r0 + i) * DIM + c0;
        *(float4*)(o)     = make_float4(acc[i][0], acc[i][1], acc[i][2], acc[i][3]);
        *(float4*)(o + 4) = make_float4(acc[i][4], acc[i][5], acc[i][6], acc[i][7]);
    }
}

__global__ __launch_bounds__(256) void reduce_kernel(
    const float* __restrict__ part, float* __restrict__ out, int ksplit)
{
    int idx = blockIdx.x * 256 + threadIdx.x;
    const float4* p = (const float4*)part;
    float4 a = p[idx];
    for (int s = 1; s < ksplit; ++s) {
        float4 q = p[(size_t)idx + (size_t)s * 262144];
        a.x += q.x; a.y += q.y; a.z += q.z; a.w += q.w;
    }
    ((float4*)out)[idx] = a;
}

extern "C" void kernel_launch(void* const* d_in, const int* in_sizes, int n_in,
                              void* d_out, int out_size, void* d_ws, size_t ws_size,
                              hipStream_t stream)
{
    const float* queries = (const float*)d_in[0];
    const float* keys    = (const float*)d_in[1];
    const float* values  = (const float*)d_in[2];
    const int*   valid   = (const int*)d_in[3];
    const float* Wql = (const float*)d_in[4];
    const float* bql = (const float*)d_in[5];
    const float* Wkl = (const float*)d_in[6];
    const float* bkl = (const float*)d_in[7];
    const float* Wqh = (const float*)d_in[8];
    const float* bqh = (const float*)d_in[9];
    const float* Wkh = (const float*)d_in[10];
    const float* bkh = (const float*)d_in[11];

    char* ws = (char*)d_ws;
    float* Smat  = (float*)(ws);                       // 64 MB
    float* q_low = (float*)(ws + 67108864);            // 512 KB
    float* k_low = (float*)(ws + 67108864 + 524288);   // 512 KB
    float* sh    = (float*)(ws + 67108864 + 1048576);  // 32 KB
    float* pm    = (float*)(ws + 67108864 + 1081344);  // 512 KB
    float* pl    = (float*)(ws + 67108864 + 1605632);  // 512 KB
    float* cmax  = (float*)(ws + 67108864 + 2129920);  // 32 KB
    float* cinv  = (float*)(ws + 67108864 + 2162688);  // 32 KB
    int*   tkidx = (int*)  (ws + 69304320);            // 256 KB

    const size_t part_off = 73400320;                  // 70 MiB
    const size_t part_sz  = (size_t)NB * SEQ * DIM * 4;
    int ksplit = 1;
    if      (ws_size >= part_off + 8 * part_sz) ksplit = 8;
    else if (ws_size >= part_off + 4 * part_sz) ksplit = 4;
    else if (ws_size >= part_off + 2 * part_sz) ksplit = 2;
    float* part = (float*)(ws + part_off);

    proj_kernel<<<dim3((NB * SEQ) / 16), 256, 0, stream>>>(
        queries, keys, Wql, bql, Wkl, bkl, Wqh, bqh, Wkh, bkh, q_low, k_low, sh);

    score_topk3<<<dim3((NB * SEQ) / 4), 256, 0, stream>>>(
        q_low, k_low, valid, Smat, tkidx);

    scatter_kernel<<<dim3((NB * SEQ * 8) / 256), 256, 0, stream>>>(
        tkidx, sh, Smat);

    colred_partial<<<dim3(SEQ / 256, 16, NB), 256, 0, stream>>>(Smat, pm, pl);

    colred_final<<<dim3((NB * SEQ) / 256), 256, 0, stream>>>(pm, pl, cmax, cinv);

    if (ksplit == 1) {
        out_kernel2<<<dim3(SEQ / QT, 1, NB), 256, 0, stream>>>(
            Smat, values, cmax, cinv, (float*)d_out, SEQ);
    } else {
        out_kernel2<<<dim3(SEQ / QT, ksplit, NB), 256, 0, stream>>>(
            Smat, values, cmax, cinv, part, SEQ / ksplit);
        reduce_kernel<<<(NB * SEQ * DIM / 4) / 256, 256, 0, stream>>>(
            part, (float*)d_out, ksplit);
    }
}